// Round 1
// baseline (379.542 us; speedup 1.0000x reference)
//
#include <hip/hip_runtime.h>
#include <hip/hip_bf16.h>
#include <stdint.h>

#define BATCH 128
#define SEQ   512
#define NW    6
#define DIM   64
#define NELEM (BATCH * SEQ * NW)   // 393216
#define PI_F  3.14159265358979323846f

typedef float v2f __attribute__((ext_vector_type(2)));
typedef uint16_t u16x8 __attribute__((ext_vector_type(8)));

__device__ __forceinline__ v2f pkfma(float s, v2f m, v2f a) {
    return __builtin_elementwise_fma((v2f){s, s}, m, a);
}

// ---------------------------------------------------------------------------
// Interleaved 6-way DPP wave-64 reduction stage. After shr1,2,4,8 +
// bcast15,31 the totals land in lane 63. (Same proven sequence as before,
// widened from 3 to 6 interleaved values.)
// ---------------------------------------------------------------------------
template <int CTRL>
__device__ __forceinline__ void red_stage6(float v[6]) {
#pragma unroll
    for (int k = 0; k < 6; ++k)
        v[k] += __int_as_float(__builtin_amdgcn_update_dpp(
            0, __float_as_int(v[k]), CTRL, 0xF, 0xF, false));
}

// Branch-free sincos(h/2), |h| <= 1. Trimmed to the bf16-output tolerance.
__device__ __forceinline__ void sincos_half(float h, float& s, float& c) {
    const float u = h * h;
    c = fmaf(u, fmaf(u, 2.6041667e-3f, -0.125f), 1.0f);
    s = h * fmaf(u, fmaf(u, 2.6041667e-4f, -2.0833333e-2f), 0.5f);
}

__device__ __forceinline__ float ldf(const void* p, int i, bool bf) {
    if (bf) {
        uint32_t u = (uint32_t)((const uint16_t*)p)[i];
        return __uint_as_float(u << 16);
    }
    return ((const float*)p)[i];
}

// ---------------------------------------------------------------------------
// Kernel 1 (msetup + misc only — the angle convert pass moved into k_sim):
//  - every block self-detects bf16-vs-f32 from the first 256 words of angles
//  - blocks [0,32): 4 waves/block evolve one (dir,col) basis column -> Mg
//  - block 32: misc fills + flag post
// ---------------------------------------------------------------------------
__global__ void k_prep(const void* ang, const void* poly, const void* fp,
                       const void* bp, const void* fc, const void* bc,
                       float* __restrict__ misc, float* __restrict__ Mg,
                       int* __restrict__ flag) {
    __shared__ int cnt;
    if (threadIdx.x == 0) cnt = 0;
    __syncthreads();
    {
        uint32_t w = ((const uint32_t*)ang)[threadIdx.x & 255];
        uint32_t e = (w >> 8) & 0xFFu;
        if (e >= 0x3Au && e <= 0x41u) atomicAdd(&cnt, 1);
    }
    __syncthreads();
    const bool bf = (cnt >= 128);

    if (blockIdx.x == 32) {
        if (threadIdx.x == 0)      misc[76] = ldf(fc, 0, bf);
        else if (threadIdx.x == 1) misc[77] = ldf(bc, 0, bf);
        else if (threadIdx.x == 2) *flag = bf ? 1 : 0;
        return;
    }

    // ---- msetup path: 4 columns per block (one per wave) ----
    const int lane = threadIdx.x & 63;
    const int tix  = blockIdx.x * 4 + (threadIdx.x >> 6);
    const int dir  = tix >> 6;
    const int col  = tix & 63;
    const void* prm = dir ? bp : fp;
    const int p = lane;

    float yr = (p == col) ? 1.f : 0.f;
    float yi = 0.f;

#pragma unroll
    for (int d = 0; d < 4; ++d) {
        const float th = 0.5f * PI_F * ldf(poly, d, bf) *
                         (float)(6 - 2 * (int)__popc((unsigned)p));
        float s, c;
        __sincosf(th, &s, &c);
        const float nr = yr * c + yi * s;
        const float ni = yi * c - yr * s;
        yr = nr; yi = ni;
#pragma unroll
        for (int k = 0; k < 6; ++k) {
            const int cw = k, tw = (k + 1) % 6;
            const int src = p ^ (((p >> (5 - cw)) & 1) << (5 - tw));
            yr = __shfl(yr, src, 64);
            yi = __shfl(yi, src, 64);
        }
    }

    int idx = 0;
#pragma unroll
    for (int l = 0; l < 2; ++l) {
#pragma unroll
        for (int w = 0; w < 6; ++w) {
            float cx, sx, cy, sy, cz, sz;
            __sincosf(0.5f * ldf(prm, idx + 0, bf), &sx, &cx);
            __sincosf(0.5f * ldf(prm, idx + 1, bf), &sy, &cy);
            __sincosf(0.5f * ldf(prm, idx + 2, bf), &sz, &cz);
            idx += 3;
            const float A = cy * cx, B = sy * sx, C = sy * cx, D = cy * sx;
            const float U00r = cz * A + sz * B, U00i = cz * B - sz * A;
            const float U11r = U00r,            U11i = sz * A - cz * B;
            const float Xr   = cz * C + sz * D, Xi   = sz * C - cz * D;
            const int m  = 1 << (5 - w);
            const int bb = (p >> (5 - w)) & 1;
            const float C1r = bb ? U11r : U00r;
            const float C1i = bb ? U11i : U00i;
            const float C2r = bb ? Xr : -Xr;
            const float C2i = Xi;
            const float pr = __shfl_xor(yr, m, 64);
            const float pi = __shfl_xor(yi, m, 64);
            const float nr = C1r * yr - C1i * yi + C2r * pr - C2i * pi;
            const float ni = C1r * yi + C1i * yr + C2r * pi + C2i * pr;
            yr = nr; yi = ni;
        }
#pragma unroll
        for (int k = 0; k < 5; ++k) {
            const int src = p ^ (((p >> (5 - k)) & 1) << (5 - (k + 1)));
            yr = __shfl(yr, src, 64);
            yi = __shfl(yi, src, 64);
        }
    }

    float* out = Mg + ((size_t)(dir * 64 + p) * 64 + (size_t)col) * 2;
    out[0] = yr;
    out[1] = yi;
}

// ---------------------------------------------------------------------------
// Kernel 2: recurrent sim — ONE wave per chain, fully wave-private.
//   * lane p holds the full M row (64 complex cols, 128 VGPRs); the 64x64
//     matvec is computed redundantly per wave via the eH(8) x eL(8) tensor
//     split: 72 pk-fma + 24 muls. No partial exchange -> ZERO barriers.
//   * measurement: per-lane v_w = ±cx_w*|y|^2 - sx_w*Re(y·conj(y^perm)),
//     (cx,sx fold linearly inside the sum) -> 6 interleaved DPP trees.
//   * partners: wire5/4 via DPP quad_perm (VALU), wires 3..1 via ds_swizzle
//     xor4/8/16, wire0 via one ds_bpermute pair (only xor32 crosses halves).
//   * z -> h broadcast via readlane(63). angles converted in-staging
//     (one-time), deleting the global cs round-trip.
// ---------------------------------------------------------------------------
__global__ void __launch_bounds__(64, 1) k_sim(const void* __restrict__ ang,
                                               const float* __restrict__ Mg,
                                               float* __restrict__ hbuf,
                                               const int* __restrict__ flag) {
    const int lane  = threadIdx.x;           // 0..63, one wave
    const int chain = blockIdx.x;            // 0..255
    const int dir   = chain >> 7;
    const int b     = chain & 127;
    const bool bf   = (*flag != 0);

    __shared__ __align__(16) float cl[SEQ * 12];   // 24 KB cos/sin(x)
    __shared__ __align__(16) float zb[SEQ * NW];   // 12 KB output buffer

    // ---- stage: convert this chain's 3072 angles -> cos/sin in LDS ----
    if (!bf) {
        const float4* src =
            (const float4*)((const float*)ang + (size_t)b * (SEQ * NW));
#pragma unroll
        for (int k = 0; k < 12; ++k) {
            const int v = k * 64 + lane;          // float4 index 0..767
            const float4 a = src[v];
            __align__(16) float o[8];
            float s, c;
            __sincosf(a.x, &s, &c); o[0] = c; o[1] = s;
            __sincosf(a.y, &s, &c); o[2] = c; o[3] = s;
            __sincosf(a.z, &s, &c); o[4] = c; o[5] = s;
            __sincosf(a.w, &s, &c); o[6] = c; o[7] = s;
            ((float4*)cl)[2 * v]     = ((const float4*)o)[0];
            ((float4*)cl)[2 * v + 1] = ((const float4*)o)[1];
        }
    } else {
        const u16x8* src =
            (const u16x8*)((const uint16_t*)ang + (size_t)b * (SEQ * NW));
#pragma unroll
        for (int k = 0; k < 6; ++k) {
            const int v = k * 64 + lane;          // u16x8 index 0..383
            const u16x8 a = src[v];
            __align__(16) float o[16];
#pragma unroll
            for (int e = 0; e < 8; ++e) {
                const float x = __uint_as_float(((uint32_t)a[e]) << 16);
                float s, c;
                __sincosf(x, &s, &c);
                o[2 * e] = c; o[2 * e + 1] = s;
            }
#pragma unroll
            for (int j = 0; j < 4; ++j)
                ((float4*)cl)[4 * v + j] = ((const float4*)o)[j];
        }
    }

    // ---- full M row for this lane: 64 complex columns (128 VGPRs) ----
    v2f Mc[64];
    {
        const float4* mr4 =
            (const float4*)(Mg + (size_t)(dir * 64 + lane) * 128);
#pragma unroll
        for (int k = 0; k < 32; ++k) {
            const float4 m = mr4[k];
            Mc[2 * k]     = (v2f){m.x, m.y};
            Mc[2 * k + 1] = (v2f){m.z, m.w};
        }
    }

    // per-wire Z sign masks + wire0 bpermute address (only xor32 needs LDS pipe
    // addressing; xor16/8/4 use ds_swizzle imm, xor2/1 use DPP quad_perm)
    int zmask[6];
#pragma unroll
    for (int w = 0; w < 6; ++w) zmask[w] = ((lane >> (5 - w)) & 1) << 31;
    const int bpa0 = (lane ^ 32) << 2;

    // walking pointers
    const float* cp = cl + (dir ? (SEQ - 1) * 12 : 0);
    const int   cstep = dir ? -12 : 12;
    float*       zp = zb + (dir ? (SEQ - 1) * NW : 0);
    const int   zstep = dir ? -NW : NW;

    float h[6] = {0.f, 0.f, 0.f, 0.f, 0.f, 0.f};

    __syncthreads();   // single wave: orders staging ds_writes before reads

    for (int t = 0; t < SEQ; ++t) {
        // this step's input cos/sin — issued early, latency hides under matvec
        const float4 xq0 = ((const float4*)cp)[0];
        const float4 xq1 = ((const float4*)cp)[1];
        const float4 xq2 = ((const float4*)cp)[2];
        cp += cstep;

        // e(h) = eH (wires 0-2, col bits 5..3) ⊗ eL (wires 3-5, col bits 2..0)
        float cw[6], sw[6];
#pragma unroll
        for (int w = 0; w < 6; ++w) sincos_half(h[w], sw[w], cw[w]);
        float g01[4], g45[4], eH[8], eL[8];
        g01[0] = cw[0] * cw[1]; g01[1] = cw[0] * sw[1];
        g01[2] = sw[0] * cw[1]; g01[3] = sw[0] * sw[1];
        g45[0] = cw[4] * cw[5]; g45[1] = cw[4] * sw[5];
        g45[2] = sw[4] * cw[5]; g45[3] = sw[4] * sw[5];
#pragma unroll
        for (int j = 0; j < 8; ++j) {
            eH[j] = g01[j >> 1] * ((j & 1) ? sw[2] : cw[2]);
            eL[j] = ((j >> 2) ? sw[3] : cw[3]) * g45[j & 3];
        }

        // y[lane] = sum_c M[lane,c] * e[c]  (two-stage contraction, 72 pkfma)
        v2f y = {0.f, 0.f};
#pragma unroll
        for (int jh = 0; jh < 8; ++jh) {
            v2f n = {0.f, 0.f};
#pragma unroll
            for (int jl = 0; jl < 8; ++jl)
                n = pkfma(eL[jl], Mc[8 * jh + jl], n);
            y = pkfma(eH[jh], n, y);
        }
        const float yr = y.x, yi = y.y;
        const int yri = __float_as_int(yr), yii = __float_as_int(yi);

        // cross-lane partners y[lane ^ (1<<(5-w))]
        float pr[6], pi[6];
        pr[0] = __int_as_float(__builtin_amdgcn_ds_bpermute(bpa0, yri));
        pi[0] = __int_as_float(__builtin_amdgcn_ds_bpermute(bpa0, yii));
        pr[1] = __int_as_float(__builtin_amdgcn_ds_swizzle(yri, 0x401F)); // xor16
        pi[1] = __int_as_float(__builtin_amdgcn_ds_swizzle(yii, 0x401F));
        pr[2] = __int_as_float(__builtin_amdgcn_ds_swizzle(yri, 0x201F)); // xor8
        pi[2] = __int_as_float(__builtin_amdgcn_ds_swizzle(yii, 0x201F));
        pr[3] = __int_as_float(__builtin_amdgcn_ds_swizzle(yri, 0x101F)); // xor4
        pi[3] = __int_as_float(__builtin_amdgcn_ds_swizzle(yii, 0x101F));
        pr[4] = __int_as_float(__builtin_amdgcn_update_dpp(0, yri, 0x4E, 0xF, 0xF, false)); // xor2
        pi[4] = __int_as_float(__builtin_amdgcn_update_dpp(0, yii, 0x4E, 0xF, 0xF, false));
        pr[5] = __int_as_float(__builtin_amdgcn_update_dpp(0, yri, 0xB1, 0xF, 0xF, false)); // xor1
        pi[5] = __int_as_float(__builtin_amdgcn_update_dpp(0, yii, 0xB1, 0xF, 0xF, false));

        const float q = fmaf(yr, yr, yi * yi);
        const float cx[6] = {xq0.x, xq0.z, xq1.x, xq1.z, xq2.x, xq2.z};
        const float sx[6] = {xq0.y, xq0.w, xq1.y, xq1.w, xq2.y, xq2.w};

        // per-lane contribution to z_w = cx*Z_w - sx*X_w (linear in the sum)
        float v[6];
#pragma unroll
        for (int w = 0; w < 6; ++w) {
            const float cq  = __int_as_float(__float_as_int(cx[w] * q) ^ zmask[w]);
            const float dot = fmaf(yr, pr[w], yi * pi[w]);
            v[w] = fmaf(-sx[w], dot, cq);
        }

        red_stage6<0x111>(v);   // row_shr:1
        red_stage6<0x112>(v);   // row_shr:2
        red_stage6<0x114>(v);   // row_shr:4
        red_stage6<0x118>(v);   // row_shr:8
        red_stage6<0x142>(v);   // row_bcast:15
        red_stage6<0x143>(v);   // row_bcast:31

        if (lane == 63) {                       // lane 63 holds the totals
#pragma unroll
            for (int w = 0; w < 6; ++w) zp[w] = v[w];
        }
        zp += zstep;
#pragma unroll
        for (int w = 0; w < 6; ++w)
            h[w] = __int_as_float(
                __builtin_amdgcn_readlane(__float_as_int(v[w]), 63));
    }

    __syncthreads();   // orders lane-63 zb writes before the bulk read

    // ---- bulk store outputs: 768 float4 over 64 lanes ----
    {
        float* orow = hbuf + (size_t)dir * NELEM + (size_t)b * (SEQ * NW);
        const float4* zs4 = (const float4*)zb;
        float4* go = (float4*)orow;
#pragma unroll
        for (int k = 0; k < 12; ++k) {
            const int idx = k * 64 + lane;
            go[idx] = zs4[idx];
        }
    }
}

// ---------------------------------------------------------------------------
// Kernel 3: out = sigmoid(fc)*h_fwd + sigmoid(bc)*h_bwd, dtype per flag.
// ---------------------------------------------------------------------------
__global__ void k_combine(const float* __restrict__ hbuf,
                          const float* __restrict__ misc,
                          void* __restrict__ out, const int* __restrict__ flag) {
    const int i = blockIdx.x * blockDim.x + threadIdx.x;
    if (i >= NELEM) return;
    const float sf = 1.f / (1.f + __expf(-misc[76]));
    const float sb = 1.f / (1.f + __expf(-misc[77]));
    const float v = sf * hbuf[i] + sb * hbuf[NELEM + i];
    if (*flag) ((__hip_bfloat16*)out)[i] = __float2bfloat16(v);
    else       ((float*)out)[i] = v;
}

// ---------------------------------------------------------------------------
extern "C" void kernel_launch(void* const* d_in, const int* in_sizes, int n_in,
                              void* d_out, int out_size, void* d_ws, size_t ws_size,
                              hipStream_t stream) {
    const void* ang  = d_in[0];
    const void* poly = d_in[1];
    const void* fp   = d_in[2];
    const void* bp   = d_in[3];
    const void* fc   = d_in[4];
    const void* bc   = d_in[5];

    // ws (floats): pad[32] | misc[128] | hbuf[2*NELEM] | Mg[16384] | flag
    float* misc = (float*)d_ws + 32;
    float* hbuf = misc + 128;
    float* Mg   = hbuf + 2 * NELEM;
    int*   flag = (int*)(Mg + 2 * 64 * 64 * 2);

    k_prep<<<33, 256, 0, stream>>>(ang, poly, fp, bp, fc, bc, misc, Mg, flag);
    k_sim<<<256, 64, 0, stream>>>(ang, Mg, hbuf, flag);
    k_combine<<<(NELEM + 255) / 256, 256, 0, stream>>>(hbuf, misc, d_out, flag);
}